// Round 6
// baseline (795.732 us; speedup 1.0000x reference)
//
#include <hip/hip_runtime.h>
#include <stdint.h>

typedef __bf16 bf16;
typedef __bf16 bf16x8 __attribute__((ext_vector_type(8)));
typedef float f32x4 __attribute__((ext_vector_type(4)));
typedef unsigned int u32;
typedef unsigned short u16;

#define DEV static __device__ __forceinline__

DEV float bf2f(u16 u){ u32 x = ((u32)u) << 16; float f; __builtin_memcpy(&f, &x, 4); return f; }

DEV float ld_f(const void* p, long i, int isb){
  return isb ? bf2f(((const u16*)p)[i]) : ((const float*)p)[i];
}

// global -> LDS direct load, 16B per lane; proper addrspace casts.
DEV void gload16(const void* g, void* l){
  __builtin_amdgcn_global_load_lds(
      (const __attribute__((address_space(1))) u32*)g,
      (__attribute__((address_space(3))) u32*)l, 16, 0, 0);
}

#define MFMA16(a,b,c) __builtin_amdgcn_mfma_f32_16x16x32_bf16(a,b,c,0,0,0)

// ---------------- dtype detect (robust to f32 or bf16 device buffers) ----------------
__global__ void k_detect(const u32* in0, int* flag){
  int t = threadIdx.x;
  int cnt = 0;
  for(int i = t; i < 1024; i += 256){
    float v = bf2f((u16)(in0[i] & 0xFFFFu));
    float a = fabsf(v);
    if(a > 0.0009f && a < 16.0f) cnt++;
  }
  __shared__ int s[256];
  s[t] = cnt; __syncthreads();
  for(int o = 128; o > 0; o >>= 1){ if(t < o) s[t] += s[t+o]; __syncthreads(); }
  if(t == 0) flag[0] = (s[0] > 512) ? 1 : 0;
}

// ---------------- cast to bf16 ----------------
__global__ void k_cast(const void* src, bf16* dst, int n, const int* flag){
  int isb = *flag;
  int i = blockIdx.x*blockDim.x + threadIdx.x;
  int stride = gridDim.x*blockDim.x;
  for(; i < n; i += stride) dst[i] = (bf16)ld_f(src, i, isb);
}

// ---------------- gather all 1-D params into one f32 region ----------------
__global__ void k_bias(const void* bq1,const void* bk1,const void* bv1,const void* bo1,
                       const void* bq2,const void* bk2,const void* bv2,const void* bo2,
                       const void* b1f,const void* b2f,
                       const void* g1,const void* be1,const void* g2,const void* be2,
                       const void* g3,const void* be3,
                       float* dst, const int* flag){
  int isb = *flag;
  int i = blockIdx.x*256 + threadIdx.x;
  if(i >= 19456) return;
  const void* s; long off;
  if(i < 3072){ if(i<1024){s=bq1;off=i;} else if(i<2048){s=bk1;off=i-1024;} else {s=bv1;off=i-2048;} }
  else if(i < 4096){s=bo1;off=i-3072;}
  else if(i < 5120){s=bq2;off=i-4096;}
  else if(i < 7168){ if(i<6144){s=bk2;off=i-5120;} else {s=bv2;off=i-6144;} }
  else if(i < 8192){s=bo2;off=i-7168;}
  else if(i < 12288){s=b1f;off=i-8192;}
  else if(i < 13312){s=b2f;off=i-12288;}
  else if(i < 14336){s=g1;off=i-13312;}
  else if(i < 15360){s=be1;off=i-14336;}
  else if(i < 16384){s=g2;off=i-15360;}
  else if(i < 17408){s=be2;off=i-16384;}
  else if(i < 18432){s=g3;off=i-17408;}
  else {s=be3;off=i-18432;}
  dst[i] = ld_f(s, off, isb);
}

// ---------------- pack: dst[(row0 + z*dstZrows + n)*Ktot + k] = src[z][k][n] ----------------
__global__ void k_pack(const void* src, bf16* dst, int K_, int N_, long srcZstride,
                       int dstZrows, int row0, int Ktot, const int* flag){
  int isb = *flag;
  __shared__ float tile[64][65];
  int bx = blockIdx.x, by = blockIdx.y, z = blockIdx.z;
  long base = (long)z * srcZstride;
  int t = threadIdx.x, tr = t >> 6, tc = t & 63;
  for(int p = 0; p < 16; p++){
    int r = p*4 + tr;
    long idx = base + (long)(bx*64 + r)*N_ + by*64 + tc;
    tile[r][tc] = ld_f(src, idx, isb);
  }
  __syncthreads();
  for(int p = 0; p < 16; p++){
    int r = p*4 + tr;
    long drow = (long)row0 + (long)z*dstZrows + by*64 + r;
    dst[drow*Ktot + bx*64 + tc] = (bf16)tile[tc][r];
  }
}

// ---------------- V transpose: dst[bh][dv][key] ----------------
__global__ void k_vtrans(const bf16* src, bf16* dst, int srcStride){
  __shared__ float tile[64][65];
  int kt = blockIdx.x, bh = blockIdx.y;
  int b = bh >> 4, h = bh & 15;
  int t = threadIdx.x, tr = t >> 6, tc = t & 63;
  const bf16* s = src + ((long)(b*1024 + kt*64))*srcStride + h*64;
  for(int p = 0; p < 16; p++){
    int r = p*4 + tr;
    tile[r][tc] = (float)s[(long)r*srcStride + tc];
  }
  __syncthreads();
  bf16* d = dst + ((long)bh*64)*1024 + kt*64;
  for(int p = 0; p < 16; p++){
    int r = p*4 + tr;
    d[(long)r*1024 + tc] = (bf16)tile[tc][r];
  }
}

// ---------------- GEMM: C[M][N] = act(A[M][K] @ Bt[N][K]^T + bias[N]) ----------------
// 128x128 tile, BK=64, 4 waves (2x2 of 64x64), global_load_lds staging with
// source-side XOR swizzle; LDS reads use the matching swizzled address.
template<int ACT>
__launch_bounds__(256)
__global__ void k_gemm(const bf16* __restrict__ A, const bf16* __restrict__ Bt,
                       const float* __restrict__ bias, bf16* __restrict__ C,
                       int M, int N, int K){
  alignas(16) __shared__ char As[16384];
  alignas(16) __shared__ char Bs[16384];
  const int tid = threadIdx.x;
  const int w = tid >> 6, l = tid & 63;
  const int wm = w >> 1, wn = w & 1;
  const int lg = l >> 4, lr = l & 15;
  const long m0 = (long)blockIdx.y * 128;
  const long n0 = (long)blockIdx.x * 128;

  f32x4 acc[4][4];
  for(int i = 0; i < 4; i++) for(int j = 0; j < 4; j++) acc[i][j] = 0.f;

  int r_st[4], cs_st[4];
  for(int i = 0; i < 4; i++){
    int o = i*4096 + tid*16;
    int r = o >> 7, c = (o >> 4) & 7;
    r_st[i] = r; cs_st[i] = (c ^ (r & 7)) * 8;
  }
  const int nk = K >> 6;
  for(int kt = 0; kt < nk; kt++){
    for(int i = 0; i < 4; i++){
      gload16(A + (m0 + r_st[i])*(long)K + kt*64 + cs_st[i], As + i*4096 + w*1024);
      gload16(Bt + (n0 + r_st[i])*(long)K + kt*64 + cs_st[i], Bs + i*4096 + w*1024);
    }
    __syncthreads();
    bf16x8 bfr[4][2];
    #pragma unroll
    for(int nf = 0; nf < 4; nf++){
      int row = wn*64 + nf*16 + lr;
      bfr[nf][0] = *(const bf16x8*)(Bs + row*128 + (((0+lg) ^ (row&7)) << 4));
      bfr[nf][1] = *(const bf16x8*)(Bs + row*128 + (((4+lg) ^ (row&7)) << 4));
    }
    #pragma unroll
    for(int mf = 0; mf < 4; mf++){
      int row = wm*64 + mf*16 + lr;
      bf16x8 a0 = *(const bf16x8*)(As + row*128 + (((0+lg) ^ (row&7)) << 4));
      bf16x8 a1 = *(const bf16x8*)(As + row*128 + (((4+lg) ^ (row&7)) << 4));
      #pragma unroll
      for(int nf = 0; nf < 4; nf++){
        acc[mf][nf] = MFMA16(a0, bfr[nf][0], acc[mf][nf]);
        acc[mf][nf] = MFMA16(a1, bfr[nf][1], acc[mf][nf]);
      }
    }
    __syncthreads();
  }
  for(int mf = 0; mf < 4; mf++){
    long mbase = m0 + wm*64 + mf*16 + lg*4;
    for(int nf = 0; nf < 4; nf++){
      long n = n0 + wn*64 + nf*16 + lr;
      float bv = bias[n];
      f32x4 a = acc[mf][nf];
      for(int j = 0; j < 4; j++){
        float v = a[j] + bv;
        if(ACT == 1) v = fmaxf(v, 0.f);
        C[(mbase + j)*(long)N + n] = (bf16)v;
      }
    }
  }
}

// ---------------- flash attention: per-wave 16 q-rows, online softmax ----------------
// grid (16, 64): x = 64-row q-block (4 waves x 16 rows), y = b*16+h.
// No __syncthreads; per-wave 2KB P-staging LDS with XOR swizzle ^((q&7)<<4).
// Fragment conventions (HW-verified via k_gemm): A row=lr, k=lg*8; B col=lr,
// k=lg*8; D row=lg*4+j, col=lr.
template<int CAUSAL>
__launch_bounds__(256)
__global__ void k_attn(const bf16* __restrict__ qb, int qStride,
                       const bf16* __restrict__ kb, int kStride,
                       const bf16* __restrict__ vt, bf16* __restrict__ out){
  alignas(16) __shared__ char pl[4*2048];
  int bh = blockIdx.y;
  int b = bh >> 4, h = bh & 15;
  int t = threadIdx.x, w = t >> 6, l = t & 63, lg = l >> 4, lr = l & 15;
  int q0 = blockIdx.x*64 + w*16;
  const bf16* qp = qb + ((long)(b*1024 + q0))*qStride + h*64;
  const bf16* kp = kb + ((long)b*1024)*kStride + h*64;
  const bf16* vp = vt + (long)bh*64*1024;
  char* pw = pl + w*2048;

  bf16x8 qa[2];
  qa[0] = *(const bf16x8*)(qp + (long)lr*qStride + lg*8);
  qa[1] = *(const bf16x8*)(qp + (long)lr*qStride + 32 + lg*8);

  f32x4 o[4];
  o[0] = 0.f; o[1] = 0.f; o[2] = 0.f; o[3] = 0.f;
  float m[4]    = {-1e30f,-1e30f,-1e30f,-1e30f};
  float lsum[4] = {0.f,0.f,0.f,0.f};

  const int nkt = CAUSAL ? ((q0 >> 6) + 1) : 16;
  for(int kt = 0; kt < nkt; kt++){
    int kt0 = kt << 6;
    // QK^T: S[16 q][64 keys]; lane holds q=lg*4+j, key=16*tt+lr
    f32x4 s4[4];
    #pragma unroll
    for(int tt = 0; tt < 4; tt++){
      s4[tt] = 0.f;
      const bf16* kr = kp + (long)(kt0 + tt*16 + lr)*kStride;
      bf16x8 kf0 = *(const bf16x8*)(kr + lg*8);
      bf16x8 kf1 = *(const bf16x8*)(kr + 32 + lg*8);
      s4[tt] = MFMA16(qa[0], kf0, s4[tt]);
      s4[tt] = MFMA16(qa[1], kf1, s4[tt]);
    }
    // scale + causal mask (only the diagonal tile can be partial)
    #pragma unroll
    for(int tt = 0; tt < 4; tt++)
      #pragma unroll
      for(int j = 0; j < 4; j++){
        float v = s4[tt][j] * 0.125f;
        if(CAUSAL && kt == nkt-1){
          int key = kt0 + tt*16 + lr;
          int qq  = q0 + lg*4 + j;
          if(key > qq) v = -1e9f;
        }
        s4[tt][j] = v;
      }
    // online softmax update (row stats across 4 regs + 16-lane lr group)
    float scal[4];
    #pragma unroll
    for(int j = 0; j < 4; j++){
      float tmax = fmaxf(fmaxf(s4[0][j], s4[1][j]), fmaxf(s4[2][j], s4[3][j]));
      tmax = fmaxf(tmax, __shfl_xor(tmax, 1));
      tmax = fmaxf(tmax, __shfl_xor(tmax, 2));
      tmax = fmaxf(tmax, __shfl_xor(tmax, 4));
      tmax = fmaxf(tmax, __shfl_xor(tmax, 8));
      float mnew = fmaxf(m[j], tmax);
      float sc = __expf(m[j] - mnew);
      m[j] = mnew;
      float rs = 0.f;
      #pragma unroll
      for(int tt = 0; tt < 4; tt++){
        float p = __expf(s4[tt][j] - mnew);
        s4[tt][j] = p;
        rs += p;
      }
      rs += __shfl_xor(rs, 1);
      rs += __shfl_xor(rs, 2);
      rs += __shfl_xor(rs, 4);
      rs += __shfl_xor(rs, 8);
      lsum[j] = lsum[j]*sc + rs;
      scal[j] = sc;
    }
    #pragma unroll
    for(int g = 0; g < 4; g++){
      f32x4 og = o[g];
      og[0] *= scal[0]; og[1] *= scal[1]; og[2] *= scal[2]; og[3] *= scal[3];
      o[g] = og;
    }
    // P -> LDS (bf16, unnormalized, swizzled)
    #pragma unroll
    for(int tt = 0; tt < 4; tt++)
      #pragma unroll
      for(int j = 0; j < 4; j++){
        int qq = lg*4 + j;
        int byte = (qq*128 + (tt*16 + lr)*2) ^ ((qq & 7) << 4);
        *(bf16*)(pw + byte) = (bf16)s4[tt][j];
      }
    // PV: read P back as A-frag (row=lr, keys lg*8 within 32-key slice)
    bf16x8 pa0 = *(const bf16x8*)(pw + ((lr*128 +      lg*16) ^ ((lr & 7) << 4)));
    bf16x8 pa1 = *(const bf16x8*)(pw + ((lr*128 + 64 + lg*16) ^ ((lr & 7) << 4)));
    #pragma unroll
    for(int g = 0; g < 4; g++){
      const bf16* vr = vp + (long)(g*16 + lr)*1024 + kt0;
      bf16x8 vf0 = *(const bf16x8*)(vr + lg*8);
      bf16x8 vf1 = *(const bf16x8*)(vr + 32 + lg*8);
      o[g] = MFMA16(pa0, vf0, o[g]);
      o[g] = MFMA16(pa1, vf1, o[g]);
    }
  }
  // epilogue: normalize + write
  bf16* ob = out + ((long)(b*1024 + q0))*1024 + h*64;
  float inv[4];
  #pragma unroll
  for(int j = 0; j < 4; j++) inv[j] = 1.0f / lsum[j];
  #pragma unroll
  for(int g = 0; g < 4; g++)
    #pragma unroll
    for(int j = 0; j < 4; j++)
      ob[(long)(lg*4 + j)*1024 + g*16 + lr] = (bf16)(o[g][j]*inv[j]);
}

// ---------------- add + layernorm; F32OUT selects output dtype ----------------
template<int F32OUT>
__global__ void k_addln(const bf16* __restrict__ a, const bf16* __restrict__ b,
                        const float* __restrict__ g, const float* __restrict__ be,
                        void* __restrict__ outv){
  int row = blockIdx.x;
  int t = threadIdx.x;
  const bf16* ar = a + (long)row*1024;
  const bf16* br = b + (long)row*1024;
  float v[4];
  float s = 0.f;
  for(int j = 0; j < 4; j++){
    int c = t*4 + j;
    v[j] = (float)ar[c] + (float)br[c];
    s += v[j];
  }
  __shared__ float red[4], red2[4];
  for(int o = 32; o > 0; o >>= 1) s += __shfl_xor(s, o);
  int w = t >> 6, l = t & 63;
  if(l == 0) red[w] = s;
  __syncthreads();
  float mean = (red[0] + red[1] + red[2] + red[3]) * (1.0f/1024.0f);
  float qv = 0.f;
  for(int j = 0; j < 4; j++){ float d = v[j] - mean; qv += d*d; }
  for(int o = 32; o > 0; o >>= 1) qv += __shfl_xor(qv, o);
  if(l == 0) red2[w] = qv;
  __syncthreads();
  float var = (red2[0] + red2[1] + red2[2] + red2[3]) * (1.0f/1024.0f);
  float inv = rsqrtf(var + 1e-5f);
  for(int j = 0; j < 4; j++){
    int c = t*4 + j;
    float r = g[c]*(v[j] - mean)*inv + be[c];
    if(F32OUT) ((float*)outv)[(long)row*1024 + c] = r;
    else       ((bf16*)outv)[(long)row*1024 + c] = (bf16)r;
  }
}

extern "C" void kernel_launch(void* const* d_in, const int* in_sizes, int n_in,
                              void* d_out, int out_size, void* d_ws, size_t ws_size,
                              hipStream_t stream){
  char* ws = (char*)d_ws;
  const long OFF_FLAG = 0;
  const long OFF_XB   = 256;
  const long OFF_ENCB = OFF_XB   + 8388608;
  const long OFF_BIAS = OFF_ENCB + 8388608;
  const long OFF_BT1  = OFF_BIAS + 131072;
  const long OFF_BTO1 = OFF_BT1  + 6291456;
  const long OFF_BTQ2 = OFF_BTO1 + 2097152;
  const long OFF_BTKV2= OFF_BTQ2 + 2097152;
  const long OFF_BTO2 = OFF_BTKV2+ 4194304;
  const long OFF_BTW1 = OFF_BTO2 + 2097152;
  const long OFF_BTW2 = OFF_BTW1 + 8388608;
  const long OFF_R    = OFF_BTW2 + 8388608;   // 33.55MB phase region
  const long OFF_Q2   = OFF_R    + 33554432;
  const long OFF_ATT  = OFF_Q2   + 8388608;
  const long OFF_PROJ = OFF_ATT  + 8388608;
  const long OFF_X1   = OFF_PROJ + 8388608;
  const long OFF_X2   = OFF_X1   + 8388608;

  const int* flag = (const int*)(ws + OFF_FLAG);
  float* biasr = (float*)(ws + OFF_BIAS);

  k_detect<<<1, 256, 0, stream>>>((const u32*)d_in[0], (int*)(ws + OFF_FLAG));
  k_cast<<<1024, 256, 0, stream>>>(d_in[0], (bf16*)(ws + OFF_XB),   4194304, flag);
  k_cast<<<1024, 256, 0, stream>>>(d_in[2], (bf16*)(ws + OFF_ENCB), 4194304, flag);
  k_bias<<<77, 256, 0, stream>>>(d_in[5], d_in[7], d_in[9], d_in[11],
                                 d_in[13], d_in[15], d_in[17], d_in[19],
                                 d_in[21], d_in[23],
                                 d_in[24], d_in[25], d_in[26], d_in[27], d_in[28], d_in[29],
                                 biasr, flag);
  k_pack<<<dim3(16,1,16), 256, 0, stream>>>(d_in[4],  (bf16*)(ws+OFF_BT1),  1024,   64, 65536L, 64,    0, 1024, flag);
  k_pack<<<dim3(16,1,16), 256, 0, stream>>>(d_in[6],  (bf16*)(ws+OFF_BT1),  1024,   64, 65536L, 64, 1024, 1024, flag);
  k_pack<<<dim3(16,1,16), 256, 0, stream>>>(d_in[8],  (bf16*)(ws+OFF_BT1),  1024,   64, 65536L, 64, 2048, 1024, flag);
  k_pack<<<dim3(16,16,1), 256, 0, stream>>>(d_in[10], (bf16*)(ws+OFF_BTO1), 1024, 1024, 0L,      0,    0, 1024, flag);
  k_pack<<<dim3(16,1,16), 256, 0, stream>>>(d_in[12], (bf16*)(ws+OFF_BTQ2), 1024,   64, 65536L, 64,    0, 1024, flag);
  k_pack<<<dim3(16,1,16), 256, 0, stream>>>(d_in[14], (bf16*)(ws+OFF_BTKV2),1024,   64, 65536L, 64,    0, 1024, flag);
  k_pack<<<dim3(16,1,16), 256, 0, stream>>>(d_in[16], (bf16*)(ws+OFF_BTKV2),1024,   64, 65536L, 64, 1024, 1024, flag);
  k_pack<<<dim3(16,16,1), 256, 0, stream>>>(d_in[18], (bf16*)(ws+OFF_BTO2), 1024, 1024, 0L,      0,    0, 1024, flag);
  k_pack<<<dim3(16,64,1), 256, 0, stream>>>(d_in[20], (bf16*)(ws+OFF_BTW1), 1024, 4096, 0L,      0,    0, 1024, flag);
  k_pack<<<dim3(64,16,1), 256, 0, stream>>>(d_in[22], (bf16*)(ws+OFF_BTW2), 4096, 1024, 0L,      0,    0, 4096, flag);

  // ---- self attention ----
  k_gemm<0><<<dim3(24,32), 256, 0, stream>>>((bf16*)(ws+OFF_XB), (bf16*)(ws+OFF_BT1),
                                             biasr + 0, (bf16*)(ws+OFF_R), 4096, 3072, 1024);
  k_vtrans<<<dim3(16,64), 256, 0, stream>>>((bf16*)(ws+OFF_R) + 2048, (bf16*)(ws+OFF_R+25165824), 3072);
  k_attn<1><<<dim3(16,64), 256, 0, stream>>>((bf16*)(ws+OFF_R), 3072,
                                             (bf16*)(ws+OFF_R) + 1024, 3072,
                                             (bf16*)(ws+OFF_R+25165824), (bf16*)(ws+OFF_ATT));
  k_gemm<0><<<dim3(8,32), 256, 0, stream>>>((bf16*)(ws+OFF_ATT), (bf16*)(ws+OFF_BTO1),
                                            biasr + 3072, (bf16*)(ws+OFF_PROJ), 4096, 1024, 1024);
  k_addln<0><<<4096, 256, 0, stream>>>((bf16*)(ws+OFF_PROJ), (bf16*)(ws+OFF_XB),
                                       biasr + 13312, biasr + 14336, (void*)(ws+OFF_X1));
  // ---- cross attention ----
  k_gemm<0><<<dim3(8,32), 256, 0, stream>>>((bf16*)(ws+OFF_X1), (bf16*)(ws+OFF_BTQ2),
                                            biasr + 4096, (bf16*)(ws+OFF_Q2), 4096, 1024, 1024);
  k_gemm<0><<<dim3(16,32), 256, 0, stream>>>((bf16*)(ws+OFF_ENCB), (bf16*)(ws+OFF_BTKV2),
                                             biasr + 5120, (bf16*)(ws+OFF_R), 4096, 2048, 1024);
  k_vtrans<<<dim3(16,64), 256, 0, stream>>>((bf16*)(ws+OFF_R) + 1024, (bf16*)(ws+OFF_R+16777216), 2048);
  k_attn<0><<<dim3(16,64), 256, 0, stream>>>((bf16*)(ws+OFF_Q2), 1024,
                                             (bf16*)(ws+OFF_R), 2048,
                                             (bf16*)(ws+OFF_R+16777216), (bf16*)(ws+OFF_ATT));
  k_gemm<0><<<dim3(8,32), 256, 0, stream>>>((bf16*)(ws+OFF_ATT), (bf16*)(ws+OFF_BTO2),
                                            biasr + 7168, (bf16*)(ws+OFF_PROJ), 4096, 1024, 1024);
  k_addln<0><<<4096, 256, 0, stream>>>((bf16*)(ws+OFF_PROJ), (bf16*)(ws+OFF_X1),
                                       biasr + 15360, biasr + 16384, (void*)(ws+OFF_X2));
  // ---- FFN ----
  k_gemm<1><<<dim3(32,32), 256, 0, stream>>>((bf16*)(ws+OFF_X2), (bf16*)(ws+OFF_BTW1),
                                             biasr + 8192, (bf16*)(ws+OFF_R), 4096, 4096, 1024);
  k_gemm<0><<<dim3(8,32), 256, 0, stream>>>((bf16*)(ws+OFF_R), (bf16*)(ws+OFF_BTW2),
                                            biasr + 12288, (bf16*)(ws+OFF_PROJ), 4096, 1024, 4096);
  k_addln<1><<<4096, 256, 0, stream>>>((bf16*)(ws+OFF_PROJ), (bf16*)(ws+OFF_X2),
                                       biasr + 17408, biasr + 18432, d_out);
}

// Round 7
// 710.164 us; speedup vs baseline: 1.1205x; 1.1205x over previous
//
#include <hip/hip_runtime.h>
#include <stdint.h>

typedef __bf16 bf16;
typedef __bf16 bf16x8 __attribute__((ext_vector_type(8)));
typedef float f32x4 __attribute__((ext_vector_type(4)));
typedef unsigned int u32;
typedef unsigned short u16;

#define DEV static __device__ __forceinline__

DEV float bf2f(u16 u){ u32 x = ((u32)u) << 16; float f; __builtin_memcpy(&f, &x, 4); return f; }

DEV float ld_f(const void* p, long i, int isb){
  return isb ? bf2f(((const u16*)p)[i]) : ((const float*)p)[i];
}

// global -> LDS direct load, 16B per lane; proper addrspace casts.
DEV void gload16(const void* g, void* l){
  __builtin_amdgcn_global_load_lds(
      (const __attribute__((address_space(1))) u32*)g,
      (__attribute__((address_space(3))) u32*)l, 16, 0, 0);
}

#define MFMA16(a,b,c) __builtin_amdgcn_mfma_f32_16x16x32_bf16(a,b,c,0,0,0)

// ---------------- dtype detect (robust to f32 or bf16 device buffers) ----------------
__global__ void k_detect(const u32* in0, int* flag){
  int t = threadIdx.x;
  int cnt = 0;
  for(int i = t; i < 1024; i += 256){
    float v = bf2f((u16)(in0[i] & 0xFFFFu));
    float a = fabsf(v);
    if(a > 0.0009f && a < 16.0f) cnt++;
  }
  __shared__ int s[256];
  s[t] = cnt; __syncthreads();
  for(int o = 128; o > 0; o >>= 1){ if(t < o) s[t] += s[t+o]; __syncthreads(); }
  if(t == 0) flag[0] = (s[0] > 512) ? 1 : 0;
}

// ---------------- cast to bf16 ----------------
__global__ void k_cast(const void* src, bf16* dst, int n, const int* flag){
  int isb = *flag;
  int i = blockIdx.x*blockDim.x + threadIdx.x;
  int stride = gridDim.x*blockDim.x;
  for(; i < n; i += stride) dst[i] = (bf16)ld_f(src, i, isb);
}

// ---------------- gather all 1-D params into one f32 region ----------------
__global__ void k_bias(const void* bq1,const void* bk1,const void* bv1,const void* bo1,
                       const void* bq2,const void* bk2,const void* bv2,const void* bo2,
                       const void* b1f,const void* b2f,
                       const void* g1,const void* be1,const void* g2,const void* be2,
                       const void* g3,const void* be3,
                       float* dst, const int* flag){
  int isb = *flag;
  int i = blockIdx.x*256 + threadIdx.x;
  if(i >= 19456) return;
  const void* s; long off;
  if(i < 3072){ if(i<1024){s=bq1;off=i;} else if(i<2048){s=bk1;off=i-1024;} else {s=bv1;off=i-2048;} }
  else if(i < 4096){s=bo1;off=i-3072;}
  else if(i < 5120){s=bq2;off=i-4096;}
  else if(i < 7168){ if(i<6144){s=bk2;off=i-5120;} else {s=bv2;off=i-6144;} }
  else if(i < 8192){s=bo2;off=i-7168;}
  else if(i < 12288){s=b1f;off=i-8192;}
  else if(i < 13312){s=b2f;off=i-12288;}
  else if(i < 14336){s=g1;off=i-13312;}
  else if(i < 15360){s=be1;off=i-14336;}
  else if(i < 16384){s=g2;off=i-15360;}
  else if(i < 17408){s=be2;off=i-16384;}
  else if(i < 18432){s=g3;off=i-17408;}
  else {s=be3;off=i-18432;}
  dst[i] = ld_f(s, off, isb);
}

// ---------------- pack: dst[(row0 + z*dstZrows + n)*Ktot + k] = src[z][k][n] ----------------
__global__ void k_pack(const void* src, bf16* dst, int K_, int N_, long srcZstride,
                       int dstZrows, int row0, int Ktot, const int* flag){
  int isb = *flag;
  __shared__ float tile[64][65];
  int bx = blockIdx.x, by = blockIdx.y, z = blockIdx.z;
  long base = (long)z * srcZstride;
  int t = threadIdx.x, tr = t >> 6, tc = t & 63;
  for(int p = 0; p < 16; p++){
    int r = p*4 + tr;
    long idx = base + (long)(bx*64 + r)*N_ + by*64 + tc;
    tile[r][tc] = ld_f(src, idx, isb);
  }
  __syncthreads();
  for(int p = 0; p < 16; p++){
    int r = p*4 + tr;
    long drow = (long)row0 + (long)z*dstZrows + by*64 + r;
    dst[drow*Ktot + bx*64 + tc] = (bf16)tile[tc][r];
  }
}

// ---------------- V transpose: dst[bh][dv][key] ----------------
__global__ void k_vtrans(const bf16* src, bf16* dst, int srcStride){
  __shared__ float tile[64][65];
  int kt = blockIdx.x, bh = blockIdx.y;
  int b = bh >> 4, h = bh & 15;
  int t = threadIdx.x, tr = t >> 6, tc = t & 63;
  const bf16* s = src + ((long)(b*1024 + kt*64))*srcStride + h*64;
  for(int p = 0; p < 16; p++){
    int r = p*4 + tr;
    tile[r][tc] = (float)s[(long)r*srcStride + tc];
  }
  __syncthreads();
  bf16* d = dst + ((long)bh*64)*1024 + kt*64;
  for(int p = 0; p < 16; p++){
    int r = p*4 + tr;
    d[(long)r*1024 + tc] = (bf16)tile[tc][r];
  }
}

// ---------------- GEMM: C[M][N] = act(A[M][K] @ Bt[N][K]^T + bias[N]) ----------------
template<int ACT>
__launch_bounds__(256)
__global__ void k_gemm(const bf16* __restrict__ A, const bf16* __restrict__ Bt,
                       const float* __restrict__ bias, bf16* __restrict__ C,
                       int M, int N, int K){
  alignas(16) __shared__ char As[16384];
  alignas(16) __shared__ char Bs[16384];
  const int tid = threadIdx.x;
  const int w = tid >> 6, l = tid & 63;
  const int wm = w >> 1, wn = w & 1;
  const int lg = l >> 4, lr = l & 15;
  const long m0 = (long)blockIdx.y * 128;
  const long n0 = (long)blockIdx.x * 128;

  f32x4 acc[4][4];
  for(int i = 0; i < 4; i++) for(int j = 0; j < 4; j++) acc[i][j] = 0.f;

  int r_st[4], cs_st[4];
  for(int i = 0; i < 4; i++){
    int o = i*4096 + tid*16;
    int r = o >> 7, c = (o >> 4) & 7;
    r_st[i] = r; cs_st[i] = (c ^ (r & 7)) * 8;
  }
  const int nk = K >> 6;
  for(int kt = 0; kt < nk; kt++){
    for(int i = 0; i < 4; i++){
      gload16(A + (m0 + r_st[i])*(long)K + kt*64 + cs_st[i], As + i*4096 + w*1024);
      gload16(Bt + (n0 + r_st[i])*(long)K + kt*64 + cs_st[i], Bs + i*4096 + w*1024);
    }
    __syncthreads();
    bf16x8 bfr[4][2];
    #pragma unroll
    for(int nf = 0; nf < 4; nf++){
      int row = wn*64 + nf*16 + lr;
      bfr[nf][0] = *(const bf16x8*)(Bs + row*128 + (((0+lg) ^ (row&7)) << 4));
      bfr[nf][1] = *(const bf16x8*)(Bs + row*128 + (((4+lg) ^ (row&7)) << 4));
    }
    #pragma unroll
    for(int mf = 0; mf < 4; mf++){
      int row = wm*64 + mf*16 + lr;
      bf16x8 a0 = *(const bf16x8*)(As + row*128 + (((0+lg) ^ (row&7)) << 4));
      bf16x8 a1 = *(const bf16x8*)(As + row*128 + (((4+lg) ^ (row&7)) << 4));
      #pragma unroll
      for(int nf = 0; nf < 4; nf++){
        acc[mf][nf] = MFMA16(a0, bfr[nf][0], acc[mf][nf]);
        acc[mf][nf] = MFMA16(a1, bfr[nf][1], acc[mf][nf]);
      }
    }
    __syncthreads();
  }
  for(int mf = 0; mf < 4; mf++){
    long mbase = m0 + wm*64 + mf*16 + lg*4;
    for(int nf = 0; nf < 4; nf++){
      long n = n0 + wn*64 + nf*16 + lr;
      float bv = bias[n];
      f32x4 a = acc[mf][nf];
      for(int j = 0; j < 4; j++){
        float v = a[j] + bv;
        if(ACT == 1) v = fmaxf(v, 0.f);
        C[(mbase + j)*(long)N + n] = (bf16)v;
      }
    }
  }
}

// ---------------- flash attention v3: per-wave 32 q-rows (2 frags share K/V) ----
// grid (64, NQB): x = bh (fastest-varying -> same-bh blocks land on one XCD,
// K/V stay L2-resident), y = 128-row q-block (4 waves x 32 rows).
// Fragment conventions (HW-verified): A row=lr, k=lg*8; D row=lg*4+j, col=lr.
template<int CAUSAL>
__launch_bounds__(256)
__global__ void k_attn(const bf16* __restrict__ qb, int qStride,
                       const bf16* __restrict__ kb, int kStride,
                       const bf16* __restrict__ vt, bf16* __restrict__ out){
  alignas(16) __shared__ char pl[4*4096];  // per-wave 4KB (2 frags x 2KB)
  int bh = blockIdx.x;
  int b = bh >> 4, h = bh & 15;
  int t = threadIdx.x, w = t >> 6, l = t & 63, lg = l >> 4, lr = l & 15;
  int q0 = blockIdx.y*128 + w*32;
  const bf16* qp = qb + ((long)(b*1024 + q0))*qStride + h*64;
  const bf16* kp = kb + ((long)b*1024)*kStride + h*64;
  const bf16* vp = vt + (long)bh*64*1024;
  char* pw = pl + w*4096;

  bf16x8 qa[2][2];
  #pragma unroll
  for(int f = 0; f < 2; f++){
    qa[f][0] = *(const bf16x8*)(qp + (long)(f*16 + lr)*qStride + lg*8);
    qa[f][1] = *(const bf16x8*)(qp + (long)(f*16 + lr)*qStride + 32 + lg*8);
  }

  f32x4 o[2][4];
  float m[2][4], lsum[2][4];
  #pragma unroll
  for(int f = 0; f < 2; f++)
    #pragma unroll
    for(int g = 0; g < 4; g++){ o[f][g] = 0.f; m[f][g] = -1e30f; lsum[f][g] = 0.f; }

  const int nkt = CAUSAL ? (((q0 + 31) >> 6) + 1) : 16;
  for(int kt = 0; kt < nkt; kt++){
    int kt0 = kt << 6;
    // K loads (shared by both q-frags)
    bf16x8 kf[4][2];
    #pragma unroll
    for(int tt = 0; tt < 4; tt++){
      const bf16* kr = kp + (long)(kt0 + tt*16 + lr)*kStride;
      kf[tt][0] = *(const bf16x8*)(kr + lg*8);
      kf[tt][1] = *(const bf16x8*)(kr + 32 + lg*8);
    }
    // QK^T for both frags
    f32x4 s4[2][4];
    #pragma unroll
    for(int f = 0; f < 2; f++)
      #pragma unroll
      for(int tt = 0; tt < 4; tt++){
        f32x4 acc = {0.f,0.f,0.f,0.f};
        acc = MFMA16(qa[f][0], kf[tt][0], acc);
        acc = MFMA16(qa[f][1], kf[tt][1], acc);
        s4[f][tt] = acc;
      }
    // scale + causal mask (only last tile partial)
    #pragma unroll
    for(int f = 0; f < 2; f++)
      #pragma unroll
      for(int tt = 0; tt < 4; tt++)
        #pragma unroll
        for(int j = 0; j < 4; j++){
          float v = s4[f][tt][j] * 0.125f;
          if(CAUSAL && kt == nkt-1){
            int key = kt0 + tt*16 + lr;
            int qq  = q0 + f*16 + lg*4 + j;
            if(key > qq) v = -1e9f;
          }
          s4[f][tt][j] = v;
        }
    // online softmax per frag
    #pragma unroll
    for(int f = 0; f < 2; f++){
      float scal[4];
      #pragma unroll
      for(int j = 0; j < 4; j++){
        float tmax = fmaxf(fmaxf(s4[f][0][j], s4[f][1][j]), fmaxf(s4[f][2][j], s4[f][3][j]));
        tmax = fmaxf(tmax, __shfl_xor(tmax, 1));
        tmax = fmaxf(tmax, __shfl_xor(tmax, 2));
        tmax = fmaxf(tmax, __shfl_xor(tmax, 4));
        tmax = fmaxf(tmax, __shfl_xor(tmax, 8));
        float mnew = fmaxf(m[f][j], tmax);
        float sc = __expf(m[f][j] - mnew);
        m[f][j] = mnew;
        float rs = 0.f;
        #pragma unroll
        for(int tt = 0; tt < 4; tt++){
          float p = __expf(s4[f][tt][j] - mnew);
          s4[f][tt][j] = p;
          rs += p;
        }
        rs += __shfl_xor(rs, 1);
        rs += __shfl_xor(rs, 2);
        rs += __shfl_xor(rs, 4);
        rs += __shfl_xor(rs, 8);
        lsum[f][j] = lsum[f][j]*sc + rs;
        scal[j] = sc;
      }
      #pragma unroll
      for(int g = 0; g < 4; g++){
        f32x4 og = o[f][g];
        og[0] *= scal[0]; og[1] *= scal[1]; og[2] *= scal[2]; og[3] *= scal[3];
        o[f][g] = og;
      }
      // P -> LDS (bf16, unnormalized, swizzled)
      #pragma unroll
      for(int tt = 0; tt < 4; tt++)
        #pragma unroll
        for(int j = 0; j < 4; j++){
          int qq = lg*4 + j;
          int byte = ((qq*128 + (tt*16 + lr)*2) ^ ((qq & 7) << 4)) + f*2048;
          *(bf16*)(pw + byte) = (bf16)s4[f][tt][j];
        }
    }
    // PV: shared V loads, both frags
    bf16x8 pa[2][2];
    #pragma unroll
    for(int f = 0; f < 2; f++){
      pa[f][0] = *(const bf16x8*)(pw + f*2048 + ((lr*128 +      lg*16) ^ ((lr & 7) << 4)));
      pa[f][1] = *(const bf16x8*)(pw + f*2048 + ((lr*128 + 64 + lg*16) ^ ((lr & 7) << 4)));
    }
    #pragma unroll
    for(int g = 0; g < 4; g++){
      const bf16* vr = vp + (long)(g*16 + lr)*1024 + kt0;
      bf16x8 vf0 = *(const bf16x8*)(vr + lg*8);
      bf16x8 vf1 = *(const bf16x8*)(vr + 32 + lg*8);
      #pragma unroll
      for(int f = 0; f < 2; f++){
        o[f][g] = MFMA16(pa[f][0], vf0, o[f][g]);
        o[f][g] = MFMA16(pa[f][1], vf1, o[f][g]);
      }
    }
  }
  // epilogue
  bf16* ob = out + ((long)(b*1024 + q0))*1024 + h*64;
  #pragma unroll
  for(int f = 0; f < 2; f++){
    float inv[4];
    #pragma unroll
    for(int j = 0; j < 4; j++) inv[j] = 1.0f / lsum[f][j];
    #pragma unroll
    for(int g = 0; g < 4; g++)
      #pragma unroll
      for(int j = 0; j < 4; j++)
        ob[(long)(f*16 + lg*4 + j)*1024 + g*16 + lr] = (bf16)(o[f][g][j]*inv[j]);
  }
}

// ---------------- add + layernorm; F32OUT selects output dtype ----------------
template<int F32OUT>
__global__ void k_addln(const bf16* __restrict__ a, const bf16* __restrict__ b,
                        const float* __restrict__ g, const float* __restrict__ be,
                        void* __restrict__ outv){
  int row = blockIdx.x;
  int t = threadIdx.x;
  const bf16* ar = a + (long)row*1024;
  const bf16* br = b + (long)row*1024;
  float v[4];
  float s = 0.f;
  for(int j = 0; j < 4; j++){
    int c = t*4 + j;
    v[j] = (float)ar[c] + (float)br[c];
    s += v[j];
  }
  __shared__ float red[4], red2[4];
  for(int o = 32; o > 0; o >>= 1) s += __shfl_xor(s, o);
  int w = t >> 6, l = t & 63;
  if(l == 0) red[w] = s;
  __syncthreads();
  float mean = (red[0] + red[1] + red[2] + red[3]) * (1.0f/1024.0f);
  float qv = 0.f;
  for(int j = 0; j < 4; j++){ float d = v[j] - mean; qv += d*d; }
  for(int o = 32; o > 0; o >>= 1) qv += __shfl_xor(qv, o);
  if(l == 0) red2[w] = qv;
  __syncthreads();
  float var = (red2[0] + red2[1] + red2[2] + red2[3]) * (1.0f/1024.0f);
  float inv = rsqrtf(var + 1e-5f);
  for(int j = 0; j < 4; j++){
    int c = t*4 + j;
    float r = g[c]*(v[j] - mean)*inv + be[c];
    if(F32OUT) ((float*)outv)[(long)row*1024 + c] = r;
    else       ((bf16*)outv)[(long)row*1024 + c] = (bf16)r;
  }
}

extern "C" void kernel_launch(void* const* d_in, const int* in_sizes, int n_in,
                              void* d_out, int out_size, void* d_ws, size_t ws_size,
                              hipStream_t stream){
  char* ws = (char*)d_ws;
  const long OFF_FLAG = 0;
  const long OFF_XB   = 256;
  const long OFF_ENCB = OFF_XB   + 8388608;
  const long OFF_BIAS = OFF_ENCB + 8388608;
  const long OFF_BT1  = OFF_BIAS + 131072;
  const long OFF_BTO1 = OFF_BT1  + 6291456;
  const long OFF_BTQ2 = OFF_BTO1 + 2097152;
  const long OFF_BTKV2= OFF_BTQ2 + 2097152;
  const long OFF_BTO2 = OFF_BTKV2+ 4194304;
  const long OFF_BTW1 = OFF_BTO2 + 2097152;
  const long OFF_BTW2 = OFF_BTW1 + 8388608;
  const long OFF_R    = OFF_BTW2 + 8388608;   // 33.55MB phase region
  const long OFF_Q2   = OFF_R    + 33554432;
  const long OFF_ATT  = OFF_Q2   + 8388608;
  const long OFF_PROJ = OFF_ATT  + 8388608;
  const long OFF_X1   = OFF_PROJ + 8388608;
  const long OFF_X2   = OFF_X1   + 8388608;

  const int* flag = (const int*)(ws + OFF_FLAG);
  float* biasr = (float*)(ws + OFF_BIAS);

  k_detect<<<1, 256, 0, stream>>>((const u32*)d_in[0], (int*)(ws + OFF_FLAG));
  k_cast<<<1024, 256, 0, stream>>>(d_in[0], (bf16*)(ws + OFF_XB),   4194304, flag);
  k_cast<<<1024, 256, 0, stream>>>(d_in[2], (bf16*)(ws + OFF_ENCB), 4194304, flag);
  k_bias<<<77, 256, 0, stream>>>(d_in[5], d_in[7], d_in[9], d_in[11],
                                 d_in[13], d_in[15], d_in[17], d_in[19],
                                 d_in[21], d_in[23],
                                 d_in[24], d_in[25], d_in[26], d_in[27], d_in[28], d_in[29],
                                 biasr, flag);
  k_pack<<<dim3(16,1,16), 256, 0, stream>>>(d_in[4],  (bf16*)(ws+OFF_BT1),  1024,   64, 65536L, 64,    0, 1024, flag);
  k_pack<<<dim3(16,1,16), 256, 0, stream>>>(d_in[6],  (bf16*)(ws+OFF_BT1),  1024,   64, 65536L, 64, 1024, 1024, flag);
  k_pack<<<dim3(16,1,16), 256, 0, stream>>>(d_in[8],  (bf16*)(ws+OFF_BT1),  1024,   64, 65536L, 64, 2048, 1024, flag);
  k_pack<<<dim3(16,16,1), 256, 0, stream>>>(d_in[10], (bf16*)(ws+OFF_BTO1), 1024, 1024, 0L,      0,    0, 1024, flag);
  k_pack<<<dim3(16,1,16), 256, 0, stream>>>(d_in[12], (bf16*)(ws+OFF_BTQ2), 1024,   64, 65536L, 64,    0, 1024, flag);
  k_pack<<<dim3(16,1,16), 256, 0, stream>>>(d_in[14], (bf16*)(ws+OFF_BTKV2),1024,   64, 65536L, 64,    0, 1024, flag);
  k_pack<<<dim3(16,1,16), 256, 0, stream>>>(d_in[16], (bf16*)(ws+OFF_BTKV2),1024,   64, 65536L, 64, 1024, 1024, flag);
  k_pack<<<dim3(16,16,1), 256, 0, stream>>>(d_in[18], (bf16*)(ws+OFF_BTO2), 1024, 1024, 0L,      0,    0, 1024, flag);
  k_pack<<<dim3(16,64,1), 256, 0, stream>>>(d_in[20], (bf16*)(ws+OFF_BTW1), 1024, 4096, 0L,      0,    0, 1024, flag);
  k_pack<<<dim3(64,16,1), 256, 0, stream>>>(d_in[22], (bf16*)(ws+OFF_BTW2), 4096, 1024, 0L,      0,    0, 4096, flag);

  // ---- self attention ----
  k_gemm<0><<<dim3(24,32), 256, 0, stream>>>((bf16*)(ws+OFF_XB), (bf16*)(ws+OFF_BT1),
                                             biasr + 0, (bf16*)(ws+OFF_R), 4096, 3072, 1024);
  k_vtrans<<<dim3(16,64), 256, 0, stream>>>((bf16*)(ws+OFF_R) + 2048, (bf16*)(ws+OFF_R+25165824), 3072);
  k_attn<1><<<dim3(64,8), 256, 0, stream>>>((bf16*)(ws+OFF_R), 3072,
                                            (bf16*)(ws+OFF_R) + 1024, 3072,
                                            (bf16*)(ws+OFF_R+25165824), (bf16*)(ws+OFF_ATT));
  k_gemm<0><<<dim3(8,32), 256, 0, stream>>>((bf16*)(ws+OFF_ATT), (bf16*)(ws+OFF_BTO1),
                                            biasr + 3072, (bf16*)(ws+OFF_PROJ), 4096, 1024, 1024);
  k_addln<0><<<4096, 256, 0, stream>>>((bf16*)(ws+OFF_PROJ), (bf16*)(ws+OFF_XB),
                                       biasr + 13312, biasr + 14336, (void*)(ws+OFF_X1));
  // ---- cross attention ----
  k_gemm<0><<<dim3(8,32), 256, 0, stream>>>((bf16*)(ws+OFF_X1), (bf16*)(ws+OFF_BTQ2),
                                            biasr + 4096, (bf16*)(ws+OFF_Q2), 4096, 1024, 1024);
  k_gemm<0><<<dim3(16,32), 256, 0, stream>>>((bf16*)(ws+OFF_ENCB), (bf16*)(ws+OFF_BTKV2),
                                             biasr + 5120, (bf16*)(ws+OFF_R), 4096, 2048, 1024);
  k_vtrans<<<dim3(16,64), 256, 0, stream>>>((bf16*)(ws+OFF_R) + 1024, (bf16*)(ws+OFF_R+16777216), 2048);
  k_attn<0><<<dim3(64,8), 256, 0, stream>>>((bf16*)(ws+OFF_Q2), 1024,
                                            (bf16*)(ws+OFF_R), 2048,
                                            (bf16*)(ws+OFF_R+16777216), (bf16*)(ws+OFF_ATT));
  k_gemm<0><<<dim3(8,32), 256, 0, stream>>>((bf16*)(ws+OFF_ATT), (bf16*)(ws+OFF_BTO2),
                                            biasr + 7168, (bf16*)(ws+OFF_PROJ), 4096, 1024, 1024);
  k_addln<0><<<4096, 256, 0, stream>>>((bf16*)(ws+OFF_PROJ), (bf16*)(ws+OFF_X1),
                                       biasr + 15360, biasr + 16384, (void*)(ws+OFF_X2));
  // ---- FFN ----
  k_gemm<1><<<dim3(32,32), 256, 0, stream>>>((bf16*)(ws+OFF_X2), (bf16*)(ws+OFF_BTW1),
                                             biasr + 8192, (bf16*)(ws+OFF_R), 4096, 4096, 1024);
  k_gemm<0><<<dim3(8,32), 256, 0, stream>>>((bf16*)(ws+OFF_R), (bf16*)(ws+OFF_BTW2),
                                            biasr + 12288, (bf16*)(ws+OFF_PROJ), 4096, 1024, 4096);
  k_addln<1><<<4096, 256, 0, stream>>>((bf16*)(ws+OFF_PROJ), (bf16*)(ws+OFF_X2),
                                       biasr + 17408, biasr + 18432, d_out);
}